// Round 1
// baseline (923.619 us; speedup 1.0000x reference)
//
#include <hip/hip_runtime.h>

#define N_NODES 100000
#define N_EDGES 1600000
#define C 128
#define LEAKY 0.01f
#define BN_EPS 1e-5f

// ---------------------------------------------------------------- init: deg=1 (self loop), zero stats
__global__ __launch_bounds__(256) void k_init(float* __restrict__ deg,
                                              float* __restrict__ sums,
                                              float* __restrict__ sumsq) {
    int i = blockIdx.x * 256 + threadIdx.x;
    if (i < N_NODES) deg[i] = 1.0f;
    if (i < C) { sums[i] = 0.0f; sumsq[i] = 0.0f; }
}

// ---------------------------------------------------------------- degree count over edge dst
__global__ __launch_bounds__(256) void k_count(const int* __restrict__ dst,
                                               float* __restrict__ deg) {
    int e = blockIdx.x * 256 + threadIdx.x;
    if (e < N_EDGES) atomicAdd(&deg[dst[e]], 1.0f);
}

// ---------------------------------------------------------------- deg -> rsqrt(deg) in place (deg>=1 always)
__global__ __launch_bounds__(256) void k_dinv(float* __restrict__ deg) {
    int i = blockIdx.x * 256 + threadIdx.x;
    if (i < N_NODES) deg[i] = rsqrtf(deg[i]);
}

// ---------------------------------------------------------------- h = x @ W  (fp32, LDS-tiled, 32 rows/block)
__global__ __launch_bounds__(256) void k_gemm(const float* __restrict__ x,
                                              const float* __restrict__ W,
                                              float* __restrict__ h) {
    __shared__ float Wl[C * C];      // 64 KB, row-major [k][c]
    __shared__ float xs[32 * C];     // 16 KB
    int tid = threadIdx.x;

    const float4* W4 = (const float4*)W;
    float4* Wl4 = (float4*)Wl;
    #pragma unroll
    for (int i = tid; i < C * C / 4; i += 256) Wl4[i] = W4[i];

    int row0 = blockIdx.x * 32;      // N_NODES % 32 == 0
    const float4* x4 = (const float4*)(x + (size_t)row0 * C);
    float4* xs4 = (float4*)xs;
    #pragma unroll
    for (int i = tid; i < 32 * C / 4; i += 256) xs4[i] = x4[i];
    __syncthreads();

    int tr = (tid >> 5) * 4;         // row block: 0..28
    int tc = (tid & 31) * 4;         // col block: 0..124
    float acc[4][4] = {};

    for (int k = 0; k < C; ++k) {
        float4 w = *(const float4*)&Wl[k * C + tc];
        float xv0 = xs[(tr + 0) * C + k];
        float xv1 = xs[(tr + 1) * C + k];
        float xv2 = xs[(tr + 2) * C + k];
        float xv3 = xs[(tr + 3) * C + k];
        acc[0][0] += xv0 * w.x; acc[0][1] += xv0 * w.y; acc[0][2] += xv0 * w.z; acc[0][3] += xv0 * w.w;
        acc[1][0] += xv1 * w.x; acc[1][1] += xv1 * w.y; acc[1][2] += xv1 * w.z; acc[1][3] += xv1 * w.w;
        acc[2][0] += xv2 * w.x; acc[2][1] += xv2 * w.y; acc[2][2] += xv2 * w.z; acc[2][3] += xv2 * w.w;
        acc[3][0] += xv3 * w.x; acc[3][1] += xv3 * w.y; acc[3][2] += xv3 * w.z; acc[3][3] += xv3 * w.w;
    }
    #pragma unroll
    for (int r = 0; r < 4; ++r) {
        *(float4*)&h[(size_t)(row0 + tr + r) * C + tc] =
            make_float4(acc[r][0], acc[r][1], acc[r][2], acc[r][3]);
    }
}

// ---------------------------------------------------------------- out init = self-loop message h[i]*dinv[i]^2
__global__ __launch_bounds__(256) void k_selfloop(const float* __restrict__ h,
                                                  const float* __restrict__ dinv,
                                                  float* __restrict__ out) {
    int i = blockIdx.x * 256 + threadIdx.x;  // float4 index, exactly N*C/4
    int n = i >> 5;                          // 32 float4 per row
    float d = dinv[n];
    float s = d * d;
    float4 v = ((const float4*)h)[i];
    ((float4*)out)[i] = make_float4(v.x * s, v.y * s, v.z * s, v.w * s);
}

// ---------------------------------------------------------------- edge scatter: out[dst] += h[src]*norm (atomics)
__global__ __launch_bounds__(256) void k_scatter(const float* __restrict__ h,
                                                 const int* __restrict__ src,
                                                 const int* __restrict__ dst,
                                                 const float* __restrict__ dinv,
                                                 float* __restrict__ out) {
    int e = blockIdx.x * 2 + (threadIdx.x >> 7);   // 2 edges/block
    int c = threadIdx.x & 127;
    int s = src[e];
    int d = dst[e];
    float nm = dinv[s] * dinv[d];
    atomicAdd(&out[(size_t)d * C + c], h[(size_t)s * C + c] * nm);
}

// ---------------------------------------------------------------- BN stats over v = leaky(out + bias)
__global__ __launch_bounds__(256) void k_stats(const float* __restrict__ out,
                                               const float* __restrict__ bias,
                                               float* __restrict__ sums,
                                               float* __restrict__ sumsq) {
    int c = threadIdx.x & 127;
    int half = threadIdx.x >> 7;
    int base = blockIdx.x * 256;
    float b = bias[c];
    float s = 0.0f, q = 0.0f;
    for (int r = half; r < 256; r += 2) {
        int n = base + r;
        if (n >= N_NODES) break;
        float v = out[(size_t)n * C + c] + b;
        v = v > 0.0f ? v : LEAKY * v;
        s += v; q += v * v;
    }
    __shared__ float ls[256], lq[256];
    ls[threadIdx.x] = s; lq[threadIdx.x] = q;
    __syncthreads();
    if (threadIdx.x < 128) {
        atomicAdd(&sums[c],  ls[threadIdx.x] + ls[threadIdx.x + 128]);
        atomicAdd(&sumsq[c], lq[threadIdx.x] + lq[threadIdx.x + 128]);
    }
}

// ---------------------------------------------------------------- fold BN params: scale/shift per channel
__global__ void k_params(const float* __restrict__ sums, const float* __restrict__ sumsq,
                         const float* __restrict__ gamma, const float* __restrict__ beta,
                         float* __restrict__ scale, float* __restrict__ shift) {
    int c = threadIdx.x;
    float inv_n = 1.0f / (float)N_NODES;
    float mean = sums[c] * inv_n;
    float var = sumsq[c] * inv_n - mean * mean;
    float sc = gamma[c] * rsqrtf(var + BN_EPS);
    scale[c] = sc;
    shift[c] = beta[c] - mean * sc;
}

// ---------------------------------------------------------------- apply: out = leaky(out+bias)*scale + shift
__global__ __launch_bounds__(256) void k_apply(float* __restrict__ out,
                                               const float* __restrict__ bias,
                                               const float* __restrict__ scale,
                                               const float* __restrict__ shift) {
    int i = blockIdx.x * 256 + threadIdx.x;  // float4 index, exactly N*C/4
    int c4 = (i & 31) * 4;
    float4 v = ((float4*)out)[i];
    float4 b  = *(const float4*)&bias[c4];
    float4 sc = *(const float4*)&scale[c4];
    float4 sh = *(const float4*)&shift[c4];
    v.x += b.x; v.x = (v.x > 0.f ? v.x : LEAKY * v.x); v.x = v.x * sc.x + sh.x;
    v.y += b.y; v.y = (v.y > 0.f ? v.y : LEAKY * v.y); v.y = v.y * sc.y + sh.y;
    v.z += b.z; v.z = (v.z > 0.f ? v.z : LEAKY * v.z); v.z = v.z * sc.z + sh.z;
    v.w += b.w; v.w = (v.w > 0.f ? v.w : LEAKY * v.w); v.w = v.w * sc.w + sh.w;
    ((float4*)out)[i] = v;
}

extern "C" void kernel_launch(void* const* d_in, const int* in_sizes, int n_in,
                              void* d_out, int out_size, void* d_ws, size_t ws_size,
                              hipStream_t stream) {
    const float* x     = (const float*)d_in[0];
    const int*   edge  = (const int*)d_in[1];
    const float* W     = (const float*)d_in[2];
    const float* bias  = (const float*)d_in[3];
    const float* gamma = (const float*)d_in[4];
    const float* beta  = (const float*)d_in[5];
    float* out = (float*)d_out;
    float* ws  = (float*)d_ws;

    // workspace layout (floats): h[N*C] | dinv[N] | sums[C] | sumsq[C] | scale[C] | shift[C]
    float* h     = ws;
    float* dinv  = h + (size_t)N_NODES * C;
    float* sums  = dinv + N_NODES;
    float* sumsq = sums + C;
    float* scale = sumsq + C;
    float* shift = scale + C;

    const int* src = edge;              // edge_index[0]
    const int* dst = edge + N_EDGES;    // edge_index[1]

    k_init    <<<(N_NODES + 255) / 256, 256, 0, stream>>>(dinv, sums, sumsq);
    k_count   <<<N_EDGES / 256,          256, 0, stream>>>(dst, dinv);
    k_dinv    <<<(N_NODES + 255) / 256, 256, 0, stream>>>(dinv);
    k_gemm    <<<N_NODES / 32,           256, 0, stream>>>(x, W, h);
    k_selfloop<<<N_NODES * C / 4 / 256,  256, 0, stream>>>(h, dinv, out);
    k_scatter <<<N_EDGES / 2,            256, 0, stream>>>(h, src, dst, dinv, out);
    k_stats   <<<(N_NODES + 255) / 256,  256, 0, stream>>>(out, bias, sums, sumsq);
    k_params  <<<1, 128,                      0, stream>>>(sums, sumsq, gamma, beta, scale, shift);
    k_apply   <<<N_NODES * C / 4 / 256,  256, 0, stream>>>(out, bias, scale, shift);
}

// Round 2
// 432.175 us; speedup vs baseline: 2.1371x; 2.1371x over previous
//
#include <hip/hip_runtime.h>

#define N_NODES 100000
#define N_EDGES 1600000
#define C 128
#define LEAKY 0.01f
#define BN_EPS 1e-5f
#define NB1 391            // ceil(N_NODES/256) — scan pass-1 blocks

// ---------------------------------------------------------------- init: zero counts, cursors, stats
__global__ __launch_bounds__(256) void k_init(int* __restrict__ cnt,
                                              int* __restrict__ cursor,
                                              float* __restrict__ sums,
                                              float* __restrict__ sumsq) {
    int i = blockIdx.x * 256 + threadIdx.x;
    if (i < N_NODES) { cnt[i] = 0; cursor[i] = 0; }
    if (i < C) { sums[i] = 0.0f; sumsq[i] = 0.0f; }
}

// ---------------------------------------------------------------- in-degree count (int atomics, L2-hot)
__global__ __launch_bounds__(256) void k_count(const int* __restrict__ dst,
                                               int* __restrict__ cnt) {
    int e = blockIdx.x * 256 + threadIdx.x;
    if (e < N_EDGES) atomicAdd(&cnt[dst[e]], 1);
}

// ---------------------------------------------------------------- dinv = rsqrt(deg+1)  (self loop)
__global__ __launch_bounds__(256) void k_dinv(const int* __restrict__ cnt,
                                              float* __restrict__ dinv) {
    int i = blockIdx.x * 256 + threadIdx.x;
    if (i < N_NODES) dinv[i] = rsqrtf((float)(cnt[i] + 1));
}

// ---------------------------------------------------------------- scan pass 1: per-block exclusive scan
__global__ __launch_bounds__(256) void k_scan1(const int* __restrict__ cnt,
                                               int* __restrict__ offs,
                                               int* __restrict__ bsum) {
    __shared__ int tmp[256];
    int i = blockIdx.x * 256 + threadIdx.x;
    int v = (i < N_NODES) ? cnt[i] : 0;
    tmp[threadIdx.x] = v;
    __syncthreads();
    for (int off = 1; off < 256; off <<= 1) {
        int t = (threadIdx.x >= off) ? tmp[threadIdx.x - off] : 0;
        __syncthreads();
        tmp[threadIdx.x] += t;
        __syncthreads();
    }
    if (i < N_NODES) offs[i] = tmp[threadIdx.x] - v;   // exclusive within block
    if (threadIdx.x == 255) bsum[blockIdx.x] = tmp[255];
}

// ---------------------------------------------------------------- scan pass 2: scan the block sums (1 block)
__global__ __launch_bounds__(512) void k_scan2(int* __restrict__ bsum) {
    __shared__ int tmp[512];
    int v = (threadIdx.x < NB1) ? bsum[threadIdx.x] : 0;
    tmp[threadIdx.x] = v;
    __syncthreads();
    for (int off = 1; off < 512; off <<= 1) {
        int t = (threadIdx.x >= off) ? tmp[threadIdx.x - off] : 0;
        __syncthreads();
        tmp[threadIdx.x] += t;
        __syncthreads();
    }
    if (threadIdx.x < NB1) bsum[threadIdx.x] = tmp[threadIdx.x] - v;  // exclusive
}

// ---------------------------------------------------------------- scan pass 3: add block offsets
__global__ __launch_bounds__(256) void k_scan3(int* __restrict__ offs,
                                               const int* __restrict__ bsum) {
    int i = blockIdx.x * 256 + threadIdx.x;
    if (i < N_NODES) offs[i] += bsum[blockIdx.x];
}

// ---------------------------------------------------------------- bucket fill: sorted_src grouped by dst
__global__ __launch_bounds__(256) void k_fill(const int* __restrict__ src,
                                              const int* __restrict__ dst,
                                              const int* __restrict__ offs,
                                              int* __restrict__ cursor,
                                              int* __restrict__ srt) {
    int e = blockIdx.x * 256 + threadIdx.x;   // N_EDGES % 256 == 0
    int d = dst[e];
    int pos = offs[d] + atomicAdd(&cursor[d], 1);
    srt[pos] = src[e];
}

// ---------------------------------------------------------------- h = x @ W  (fp32, LDS-tiled, 32 rows/block)
__global__ __launch_bounds__(256) void k_gemm(const float* __restrict__ x,
                                              const float* __restrict__ W,
                                              float* __restrict__ h) {
    __shared__ float Wl[C * C];      // 64 KB, row-major [k][c]
    __shared__ float xs[32 * C];     // 16 KB
    int tid = threadIdx.x;

    const float4* W4 = (const float4*)W;
    float4* Wl4 = (float4*)Wl;
    #pragma unroll
    for (int i = tid; i < C * C / 4; i += 256) Wl4[i] = W4[i];

    int row0 = blockIdx.x * 32;      // N_NODES % 32 == 0
    const float4* x4 = (const float4*)(x + (size_t)row0 * C);
    float4* xs4 = (float4*)xs;
    #pragma unroll
    for (int i = tid; i < 32 * C / 4; i += 256) xs4[i] = x4[i];
    __syncthreads();

    int tr = (tid >> 5) * 4;         // row block: 0..28
    int tc = (tid & 31) * 4;         // col block: 0..124
    float acc[4][4] = {};

    for (int k = 0; k < C; ++k) {
        float4 w = *(const float4*)&Wl[k * C + tc];
        float xv0 = xs[(tr + 0) * C + k];
        float xv1 = xs[(tr + 1) * C + k];
        float xv2 = xs[(tr + 2) * C + k];
        float xv3 = xs[(tr + 3) * C + k];
        acc[0][0] += xv0 * w.x; acc[0][1] += xv0 * w.y; acc[0][2] += xv0 * w.z; acc[0][3] += xv0 * w.w;
        acc[1][0] += xv1 * w.x; acc[1][1] += xv1 * w.y; acc[1][2] += xv1 * w.z; acc[1][3] += xv1 * w.w;
        acc[2][0] += xv2 * w.x; acc[2][1] += xv2 * w.y; acc[2][2] += xv2 * w.z; acc[2][3] += xv2 * w.w;
        acc[3][0] += xv3 * w.x; acc[3][1] += xv3 * w.y; acc[3][2] += xv3 * w.z; acc[3][3] += xv3 * w.w;
    }
    #pragma unroll
    for (int r = 0; r < 4; ++r) {
        *(float4*)&h[(size_t)(row0 + tr + r) * C + tc] =
            make_float4(acc[r][0], acc[r][1], acc[r][2], acc[r][3]);
    }
}

// ---------------------------------------------------------------- CSR aggregate: 32 lanes per dst node
// out[d] = leaky( dinv[d]^2*h[d] + sum_bucket dinv[d]*dinv[s]*h[s] + bias )
__global__ __launch_bounds__(256) void k_aggregate(const float* __restrict__ h,
                                                   const int* __restrict__ srt,
                                                   const int* __restrict__ offs,
                                                   const int* __restrict__ cnt,
                                                   const float* __restrict__ dinv,
                                                   const float* __restrict__ bias,
                                                   float* __restrict__ out) {
    int node = blockIdx.x * 8 + (threadIdx.x >> 5);   // N_NODES % 8 == 0
    int lane = threadIdx.x & 31;
    const float4* h4 = (const float4*)h;

    float dn = dinv[node];
    float4 v = h4[(size_t)node * 32 + lane];          // self-loop message
    float sl = dn * dn;
    float4 acc = make_float4(v.x * sl, v.y * sl, v.z * sl, v.w * sl);

    int beg = offs[node];
    int end = beg + cnt[node];
    for (int k = beg; k < end; ++k) {
        int s = srt[k];
        float nm = dn * dinv[s];
        float4 m = h4[(size_t)s * 32 + lane];
        acc.x += nm * m.x; acc.y += nm * m.y; acc.z += nm * m.z; acc.w += nm * m.w;
    }

    float4 b = ((const float4*)bias)[lane];
    acc.x += b.x; acc.y += b.y; acc.z += b.z; acc.w += b.w;
    acc.x = acc.x > 0.f ? acc.x : LEAKY * acc.x;
    acc.y = acc.y > 0.f ? acc.y : LEAKY * acc.y;
    acc.z = acc.z > 0.f ? acc.z : LEAKY * acc.z;
    acc.w = acc.w > 0.f ? acc.w : LEAKY * acc.w;
    ((float4*)out)[(size_t)node * 32 + lane] = acc;
}

// ---------------------------------------------------------------- BN stats over v (already leaky(·+bias))
__global__ __launch_bounds__(256) void k_stats(const float* __restrict__ out,
                                               float* __restrict__ sums,
                                               float* __restrict__ sumsq) {
    int c = threadIdx.x & 127;
    int half = threadIdx.x >> 7;
    int base = blockIdx.x * 256;
    float s = 0.0f, q = 0.0f;
    for (int r = half; r < 256; r += 2) {
        int n = base + r;
        if (n >= N_NODES) break;
        float v = out[(size_t)n * C + c];
        s += v; q += v * v;
    }
    __shared__ float ls[256], lq[256];
    ls[threadIdx.x] = s; lq[threadIdx.x] = q;
    __syncthreads();
    if (threadIdx.x < 128) {
        atomicAdd(&sums[c],  ls[threadIdx.x] + ls[threadIdx.x + 128]);
        atomicAdd(&sumsq[c], lq[threadIdx.x] + lq[threadIdx.x + 128]);
    }
}

// ---------------------------------------------------------------- fold BN params
__global__ void k_params(const float* __restrict__ sums, const float* __restrict__ sumsq,
                         const float* __restrict__ gamma, const float* __restrict__ beta,
                         float* __restrict__ scale, float* __restrict__ shift) {
    int c = threadIdx.x;
    float inv_n = 1.0f / (float)N_NODES;
    float mean = sums[c] * inv_n;
    float var = sumsq[c] * inv_n - mean * mean;
    float sc = gamma[c] * rsqrtf(var + BN_EPS);
    scale[c] = sc;
    shift[c] = beta[c] - mean * sc;
}

// ---------------------------------------------------------------- apply: out = out*scale + shift
__global__ __launch_bounds__(256) void k_apply(float* __restrict__ out,
                                               const float* __restrict__ scale,
                                               const float* __restrict__ shift) {
    int i = blockIdx.x * 256 + threadIdx.x;  // float4 index, exactly N*C/4
    int c4 = i & 31;
    float4 v = ((float4*)out)[i];
    float4 sc = ((const float4*)scale)[c4];
    float4 sh = ((const float4*)shift)[c4];
    v.x = v.x * sc.x + sh.x;
    v.y = v.y * sc.y + sh.y;
    v.z = v.z * sc.z + sh.z;
    v.w = v.w * sc.w + sh.w;
    ((float4*)out)[i] = v;
}

extern "C" void kernel_launch(void* const* d_in, const int* in_sizes, int n_in,
                              void* d_out, int out_size, void* d_ws, size_t ws_size,
                              hipStream_t stream) {
    const float* x     = (const float*)d_in[0];
    const int*   edge  = (const int*)d_in[1];
    const float* W     = (const float*)d_in[2];
    const float* bias  = (const float*)d_in[3];
    const float* gamma = (const float*)d_in[4];
    const float* beta  = (const float*)d_in[5];
    float* out = (float*)d_out;
    char* ws = (char*)d_ws;

    // workspace layout
    float* h      = (float*)ws;                               ws += (size_t)N_NODES * C * 4;   // 51.2 MB
    int*   srt    = (int*)ws;                                 ws += (size_t)N_EDGES * 4;       // 6.4 MB
    int*   cnt    = (int*)ws;                                 ws += (size_t)N_NODES * 4;
    int*   offs   = (int*)ws;                                 ws += (size_t)N_NODES * 4;
    int*   cursor = (int*)ws;                                 ws += (size_t)N_NODES * 4;
    int*   bsum   = (int*)ws;                                 ws += 512 * 4;
    float* dinv   = (float*)ws;                               ws += (size_t)N_NODES * 4;
    float* sums   = (float*)ws;                               ws += C * 4;
    float* sumsq  = (float*)ws;                               ws += C * 4;
    float* scale  = (float*)ws;                               ws += C * 4;
    float* shift  = (float*)ws;

    const int* src = edge;              // edge_index[0]
    const int* dst = edge + N_EDGES;    // edge_index[1]

    k_init     <<<NB1,                 256, 0, stream>>>(cnt, cursor, sums, sumsq);
    k_count    <<<N_EDGES / 256,       256, 0, stream>>>(dst, cnt);
    k_dinv     <<<NB1,                 256, 0, stream>>>(cnt, dinv);
    k_scan1    <<<NB1,                 256, 0, stream>>>(cnt, offs, bsum);
    k_scan2    <<<1,                   512, 0, stream>>>(bsum);
    k_scan3    <<<NB1,                 256, 0, stream>>>(offs, bsum);
    k_fill     <<<N_EDGES / 256,       256, 0, stream>>>(src, dst, offs, cursor, srt);
    k_gemm     <<<N_NODES / 32,        256, 0, stream>>>(x, W, h);
    k_aggregate<<<N_NODES / 8,         256, 0, stream>>>(h, srt, offs, cnt, dinv, bias, out);
    k_stats    <<<NB1,                 256, 0, stream>>>(out, sums, sumsq);
    k_params   <<<1, 128,                   0, stream>>>(sums, sumsq, gamma, beta, scale, shift);
    k_apply    <<<N_NODES * C / 4 / 256, 256, 0, stream>>>(out, scale, shift);
}